// Round 15
// baseline (595.701 us; speedup 1.0000x reference)
//
#include <hip/hip_runtime.h>
#include <math.h>

#define N_NODES 100000
#define N_EDGES 400000
#define N_GRAPHS_C 4096
#define E_TOT (N_EDGES + N_NODES)

static inline int ceil_div(int a, int b) { return (a + b - 1) / b; }

typedef __attribute__((ext_vector_type(8))) short short8v;
typedef __attribute__((ext_vector_type(4))) float float4v;

#define GLL16(g, l)                                                                          \
  __builtin_amdgcn_global_load_lds((const __attribute__((address_space(1))) unsigned int*)(g), \
                                   (__attribute__((address_space(3))) unsigned int*)(l), 16, 0, 0)

__device__ __forceinline__ float b2f(unsigned short u) {
  union { unsigned int i; float f; } v;
  v.i = ((unsigned int)u) << 16;
  return v.f;
}
__device__ __forceinline__ unsigned short f2b(float f) {
  union { float f; unsigned int i; } v;
  v.f = f;
  unsigned int x = v.i;
  unsigned int r = x + 0x7fffu + ((x >> 16) & 1u);  // RNE
  return (unsigned short)(r >> 16);
}

// ---------------- conversions + degree/graph counting, one launch ----------------

__device__ __forceinline__ void cvt_one(const float* __restrict__ W, unsigned short* __restrict__ Wt,
                                        int K, int Ncol, int idx) {
  int n = idx / K, k = idx % K;
  Wt[(size_t)n * K + k] = f2b(W[(size_t)k * Ncol + n]);
}

__device__ __forceinline__ void wa_one(const float* __restrict__ W, const float* __restrict__ a_s,
                                       const float* __restrict__ a_d, unsigned short* __restrict__ wt,
                                       int K, int Ncol, int H, int C, int idx) {
  int k = idx % K;
  int j = idx / K;  // 0..2H-1
  const float* a = (j < H) ? a_s : a_d;
  int h = (j < H) ? j : j - H;
  float s = 0.f;
  for (int c = 0; c < C; c++) s += W[(size_t)k * Ncol + h * C + c] * a[h * C + c];
  wt[(size_t)(Ncol + j) * K + k] = f2b(s);
}

__global__ __launch_bounds__(256) void k_cvt_all(
    const float* __restrict__ x, unsigned short* __restrict__ xb,
    const float* __restrict__ W0, const float* __restrict__ as0, const float* __restrict__ ad0, unsigned short* __restrict__ wt0,
    const float* __restrict__ W1, const float* __restrict__ as1, const float* __restrict__ ad1, unsigned short* __restrict__ wt1,
    const float* __restrict__ W2, const float* __restrict__ as2, const float* __restrict__ ad2, unsigned short* __restrict__ wt2,
    const float* __restrict__ W3, const float* __restrict__ as3, const float* __restrict__ ad3, unsigned short* __restrict__ wt3,
    const int* __restrict__ ei, int* __restrict__ deg,
    const int* __restrict__ batch, int* __restrict__ gcnt) {
  int i = blockIdx.x * 256 + threadIdx.x;
  const int nx = N_NODES * 64 / 4;
  const int w0e = nx + 64 * 256;
  const int w1e = w0e + 256 * 256;
  const int w2e = w1e + 256 * 256;
  const int w3e = w2e + 256 * 128;
  const int a0e = w3e + 64 * 8;
  const int a1e = a0e + 256 * 8;
  const int a2e = a1e + 256 * 8;
  const int a3e = a2e + 256 * 2;
  const int dege = a3e + N_EDGES;
  const int gce = dege + N_NODES;
  if (i < nx) {
    float4 v = *(const float4*)(x + (size_t)i * 4);
    ushort4 o;
    o.x = f2b(v.x); o.y = f2b(v.y); o.z = f2b(v.z); o.w = f2b(v.w);
    *(ushort4*)(xb + (size_t)i * 4) = o;
  } else if (i < w0e) cvt_one(W0, wt0, 64, 256, i - nx);
  else if (i < w1e) cvt_one(W1, wt1, 256, 256, i - w0e);
  else if (i < w2e) cvt_one(W2, wt2, 256, 256, i - w1e);
  else if (i < w3e) cvt_one(W3, wt3, 256, 128, i - w2e);
  else if (i < a0e) wa_one(W0, as0, ad0, wt0, 64, 256, 4, 64, i - w3e);
  else if (i < a1e) wa_one(W1, as1, ad1, wt1, 256, 256, 4, 64, i - a0e);
  else if (i < a2e) wa_one(W2, as2, ad2, wt2, 256, 256, 4, 64, i - a1e);
  else if (i < a3e) wa_one(W3, as3, ad3, wt3, 256, 128, 1, 128, i - a2e);
  else if (i < dege) atomicAdd(&deg[ei[N_EDGES + (i - a3e)]], 1);
  else if (i < gce) atomicAdd(&gcnt[batch[i - dege]], 1);
}

// ---------------- CSR build ----------------

__global__ __launch_bounds__(256) void k_scan(int* __restrict__ deg, int* __restrict__ offs,
                                              int* __restrict__ cursor, int* __restrict__ counter) {
  __shared__ int sm[256];
  __shared__ int sbase;
  int tid = threadIdx.x;
  int n = blockIdx.x * 256 + tid;
  int d = (n < N_NODES) ? (deg[n] + 1) : 0;  // +1 self loop
  sm[tid] = d;
  __syncthreads();
  for (int off = 1; off < 256; off <<= 1) {
    int v = (tid >= off) ? sm[tid - off] : 0;
    __syncthreads();
    sm[tid] += v;
    __syncthreads();
  }
  if (tid == 255) sbase = atomicAdd(counter, sm[255]);
  __syncthreads();
  int excl = sm[tid] - d;
  if (n < N_NODES) {
    int o = sbase + excl;
    offs[n] = o;
    cursor[n] = o;
    deg[n] = d;
  }
}

__global__ __launch_bounds__(256) void k_scatter(const int* __restrict__ ei, int* __restrict__ cursor,
                                                 int* __restrict__ csr) {
  int i = blockIdx.x * 256 + threadIdx.x;
  if (i < N_EDGES) {
    int d = ei[N_EDGES + i];
    int pos = atomicAdd(&cursor[d], 1);
    csr[pos] = ei[i];
  } else if (i < E_TOT) {
    int n = i - N_EDGES;
    int pos = atomicAdd(&cursor[n], 1);
    csr[pos] = n;  // self loop
  }
}

__global__ __launch_bounds__(256) void k_gscan(const int* __restrict__ gcnt, int* __restrict__ gptr) {
  __shared__ int sm[256];
  __shared__ int srun;
  int tid = threadIdx.x;
  if (tid == 0) srun = 0;
  __syncthreads();
  for (int c = 0; c < N_GRAPHS_C / 256; c++) {
    int idx = c * 256 + tid;
    int v = gcnt[idx];
    sm[tid] = v;
    __syncthreads();
    for (int off = 1; off < 256; off <<= 1) {
      int t = (tid >= off) ? sm[tid - off] : 0;
      __syncthreads();
      sm[tid] += t;
      __syncthreads();
    }
    gptr[idx] = srun + sm[tid] - v;
    __syncthreads();
    if (tid == 0) srun += sm[255];
    __syncthreads();
  }
}

// ---------------- bf16 MFMA GEMM, async staging, transposed-C epilogue ----------------
// Main acc uses SWAPPED operands: acc[i][j] = mfma(bf[j], af[i], .) so lane l16
// holds output ROW (wrow+i*16+l16) and quad*4+r indexes 4 CONSECUTIVE columns
// -> C-write is 16 packed ushort4 (8B) stores instead of 64 scalar 2B stores.
// acc_e (es/ed) keeps original operand order (row=quad*4+r, ext-col=l16).

template <int ATT>
__global__ __launch_bounds__(256) void k_gemm_bf16(const unsigned short* __restrict__ A,
                                                   const unsigned short* __restrict__ Wt,
                                                   unsigned short* __restrict__ out, int M, int K, int Ncol,
                                                   float* __restrict__ es, float* __restrict__ ed) {
  __shared__ unsigned short As[128 * 32];
  __shared__ unsigned short Bs[144 * 32];
  int tid = threadIdx.x;
  int wave = tid >> 6, lane = tid & 63;
  int quad = lane >> 4, l16 = lane & 15;
  int wrow = (wave & 1) * 64, wcol = (wave >> 1) * 64;
  int row0 = blockIdx.x * 128, col0 = blockIdx.y * 128;

  constexpr int EX = (ATT == 1) ? 8 : 2;
  bool blockExtra = (ATT == 1) ? (blockIdx.y == 1) : true;

  float4v acc[4][4];
#pragma unroll
  for (int i = 0; i < 4; i++)
#pragma unroll
    for (int j = 0; j < 4; j++) acc[i][j] = (float4v)(0.f);
  float4v acc_e[4];
#pragma unroll
  for (int i = 0; i < 4; i++) acc_e[i] = (float4v)(0.f);

  int lrow = lane >> 2;
  int lcb = (lane & 3) * 8;
  int ca = wave, cb = wave + 4;

  for (int k0 = 0; k0 < K; k0 += 32) {
    GLL16(A + (size_t)(row0 + ca * 16 + lrow) * K + k0 + lcb, &As[ca * 512]);
    GLL16(A + (size_t)(row0 + cb * 16 + lrow) * K + k0 + lcb, &As[cb * 512]);
    GLL16(Wt + (size_t)(col0 + ca * 16 + lrow) * K + k0 + lcb, &Bs[ca * 512]);
    GLL16(Wt + (size_t)(col0 + cb * 16 + lrow) * K + k0 + lcb, &Bs[cb * 512]);
    if (blockExtra && wave == 0)
      GLL16(Wt + (size_t)(Ncol + lrow) * K + k0 + lcb, &Bs[8 * 512]);
    __syncthreads();

    short8v af[4], bf[4];
#pragma unroll
    for (int i = 0; i < 4; i++)
      af[i] = *(const short8v*)(&As[(wrow + i * 16 + l16) * 32 + quad * 8]);
#pragma unroll
    for (int j = 0; j < 4; j++)
      bf[j] = *(const short8v*)(&Bs[(wcol + j * 16 + l16) * 32 + quad * 8]);
#pragma unroll
    for (int i = 0; i < 4; i++)
#pragma unroll
      for (int j = 0; j < 4; j++)
        acc[i][j] = __builtin_amdgcn_mfma_f32_16x16x32_bf16(bf[j], af[i], acc[i][j], 0, 0, 0);
    if (blockExtra && wcol == 0) {
      short8v bfe = *(const short8v*)(&Bs[(128 + l16) * 32 + quad * 8]);
#pragma unroll
      for (int i = 0; i < 4; i++)
        acc_e[i] = __builtin_amdgcn_mfma_f32_16x16x32_bf16(af[i], bfe, acc_e[i], 0, 0, 0);
    }
    __syncthreads();
  }

  // packed C-write: lane l16 = row, quad*4+r = 4 consecutive cols
#pragma unroll
  for (int i = 0; i < 4; i++) {
    int m = row0 + wrow + i * 16 + l16;
    if (m < M) {
#pragma unroll
      for (int j = 0; j < 4; j++) {
        ushort4 o;
        o.x = f2b(acc[i][j][0]);
        o.y = f2b(acc[i][j][1]);
        o.z = f2b(acc[i][j][2]);
        o.w = f2b(acc[i][j][3]);
        *(ushort4*)(out + (size_t)m * Ncol + col0 + wcol + j * 16 + quad * 4) = o;
      }
    }
  }

  if (blockExtra && wcol == 0 && l16 < EX) {
    constexpr int H = (ATT == 1) ? 4 : 1;
    float* dst = (l16 < H) ? es : ed;
    int h = (l16 < H) ? l16 : l16 - H;
#pragma unroll
    for (int i = 0; i < 4; i++) {
#pragma unroll
      for (int r = 0; r < 4; r++) {
        int m = row0 + wrow + i * 16 + quad * 4 + r;
        if (m < M) dst[m * H + h] = acc_e[i][r];
      }
    }
  }
}

// ---------------- fused logits + softmax + aggregation ----------------

__device__ __forceinline__ void acc4(float* acc, float w, uint2 u) {
  acc[0] += w * b2f((unsigned short)(u.x & 0xffff));
  acc[1] += w * b2f((unsigned short)(u.x >> 16));
  acc[2] += w * b2f((unsigned short)(u.y & 0xffff));
  acc[3] += w * b2f((unsigned short)(u.y >> 16));
}
__device__ __forceinline__ void acc2(float* acc, float w, unsigned int u) {
  acc[0] += w * b2f((unsigned short)(u & 0xffff));
  acc[1] += w * b2f((unsigned short)(u >> 16));
}
__device__ __forceinline__ float lrelu_exp(float e) {
  e = e > 0.f ? e : 0.2f * e;
  return __expf(e);
}

template <int H, int C>
__global__ __launch_bounds__(256) void k_aggregate(const unsigned short* __restrict__ hbuf,
                                                   const float* __restrict__ es, const float* __restrict__ ed,
                                                   const int* __restrict__ offs, const int* __restrict__ deg,
                                                   const int* __restrict__ csr, const float* __restrict__ bias,
                                                   unsigned short* __restrict__ out, int applyElu) {
  constexpr int F = H * C;
  constexpr int VPL = F / 64;  // 4 (H=4,C=64) or 2 (H=1,C=128)
  int wave = threadIdx.x >> 6;
  int lane = threadIdx.x & 63;
  int n = blockIdx.x * 4 + wave;
  if (n >= N_NODES) return;
  int head = (H == 1) ? 0 : (lane >> 4);
  int start = offs[n];
  int cnt = deg[n];
  const int* csrp = csr + start;
  float edn = ed[n * H + head];

  float acc[VPL];
#pragma unroll
  for (int j = 0; j < VPL; j++) acc[j] = 0.f;
  float dsum = 0.f;

  int i = 0;
  for (; i + 4 <= cnt; i += 4) {
    int s0 = csrp[i], s1 = csrp[i + 1], s2 = csrp[i + 2], s3 = csrp[i + 3];
    float w0 = lrelu_exp(es[s0 * H + head] + edn);
    float w1 = lrelu_exp(es[s1 * H + head] + edn);
    float w2 = lrelu_exp(es[s2 * H + head] + edn);
    float w3 = lrelu_exp(es[s3 * H + head] + edn);
    dsum += (w0 + w1) + (w2 + w3);
    if (VPL == 4) {
      uint2 u0 = *(const uint2*)(hbuf + (size_t)s0 * F + lane * 4);
      uint2 u1 = *(const uint2*)(hbuf + (size_t)s1 * F + lane * 4);
      uint2 u2 = *(const uint2*)(hbuf + (size_t)s2 * F + lane * 4);
      uint2 u3 = *(const uint2*)(hbuf + (size_t)s3 * F + lane * 4);
      acc4(acc, w0, u0); acc4(acc, w1, u1); acc4(acc, w2, u2); acc4(acc, w3, u3);
    } else {
      unsigned int u0 = *(const unsigned int*)(hbuf + (size_t)s0 * F + lane * 2);
      unsigned int u1 = *(const unsigned int*)(hbuf + (size_t)s1 * F + lane * 2);
      unsigned int u2 = *(const unsigned int*)(hbuf + (size_t)s2 * F + lane * 2);
      unsigned int u3 = *(const unsigned int*)(hbuf + (size_t)s3 * F + lane * 2);
      acc2(acc, w0, u0); acc2(acc, w1, u1); acc2(acc, w2, u2); acc2(acc, w3, u3);
    }
  }
  for (; i < cnt; i++) {
    int s = csrp[i];
    float w = lrelu_exp(es[s * H + head] + edn);
    dsum += w;
    if (VPL == 4) {
      uint2 u = *(const uint2*)(hbuf + (size_t)s * F + lane * 4);
      acc4(acc, w, u);
    } else {
      unsigned int u = *(const unsigned int*)(hbuf + (size_t)s * F + lane * 2);
      acc2(acc, w, u);
    }
  }

  float iv = 1.0f / fmaxf(dsum, 1e-16f);
  unsigned short ob[VPL];
#pragma unroll
  for (int j = 0; j < VPL; j++) {
    float v = acc[j] * iv + bias[lane * VPL + j];
    if (applyElu) v = v > 0.f ? v : expm1f(v);
    ob[j] = f2b(v);
  }
  if (VPL == 4) {
    ushort4 o = make_ushort4(ob[0], ob[1], ob[2], ob[3]);
    *(ushort4*)(out + (size_t)n * F + lane * 4) = o;
  } else {
    ushort2 o = make_ushort2(ob[0], ob[1]);
    *(ushort2*)(out + (size_t)n * F + lane * 2) = o;
  }
}

// ---------------- fused per-graph mean pool + MLP readout ----------------

__global__ __launch_bounds__(128) void k_pool_readout(const unsigned short* __restrict__ feat,
                                                      const int* __restrict__ gptr, const int* __restrict__ gcnt,
                                                      const float* __restrict__ mW0, const float* __restrict__ mb0,
                                                      const float* __restrict__ mW1, const float* __restrict__ mb1,
                                                      const float* __restrict__ mW2, const float* __restrict__ mb2,
                                                      float* __restrict__ out) {
  __shared__ float part[2][128];
  __shared__ float p[128];
  __shared__ float y1[64];
  __shared__ float y2[32];
  int g = blockIdx.x;
  int t = threadIdx.x;
  int w = t >> 6, lane = t & 63;
  int start = gptr[g];
  int c = gcnt[g];
  float a0 = 0.f, a1 = 0.f;
  for (int i = w; i < c; i += 2) {
    unsigned int u = *(const unsigned int*)(feat + (size_t)(start + i) * 128 + lane * 2);
    a0 += b2f((unsigned short)(u & 0xffff));
    a1 += b2f((unsigned short)(u >> 16));
  }
  part[w][lane * 2 + 0] = a0;
  part[w][lane * 2 + 1] = a1;
  __syncthreads();
  float invc = 1.0f / fmaxf((float)c, 1.0f);
  p[t] = (part[0][t] + part[1][t]) * invc;
  __syncthreads();
  if (t < 64) {
    float v = mb0[t];
#pragma unroll 4
    for (int k = 0; k < 128; k++) v += p[k] * mW0[k * 64 + t];
    y1[t] = v > 0.f ? v : 0.f;
  }
  __syncthreads();
  if (t < 32) {
    float v = mb1[t];
#pragma unroll 4
    for (int k = 0; k < 64; k++) v += y1[k] * mW1[k * 32 + t];
    y2[t] = v > 0.f ? v : 0.f;
  }
  __syncthreads();
  if (t < 4) {
    float v = mb2[t];
#pragma unroll 4
    for (int k = 0; k < 32; k++) v += y2[k] * mW2[k * 4 + t];
    out[(size_t)g * 4 + t] = v;
  }
}

// ---------------- host side ----------------

extern "C" void kernel_launch(void* const* d_in, const int* in_sizes, int n_in,
                              void* d_out, int out_size, void* d_ws, size_t ws_size,
                              hipStream_t stream) {
  const float* x = (const float*)d_in[0];
  const int* ei = (const int*)d_in[1];
  const int* batch = (const int*)d_in[2];
  const float* W0 = (const float*)d_in[4];
  const float* as0 = (const float*)d_in[5];
  const float* ad0 = (const float*)d_in[6];
  const float* b0 = (const float*)d_in[7];
  const float* W1 = (const float*)d_in[8];
  const float* as1 = (const float*)d_in[9];
  const float* ad1 = (const float*)d_in[10];
  const float* b1 = (const float*)d_in[11];
  const float* W2 = (const float*)d_in[12];
  const float* as2 = (const float*)d_in[13];
  const float* ad2 = (const float*)d_in[14];
  const float* b2 = (const float*)d_in[15];
  const float* W3 = (const float*)d_in[16];
  const float* as3 = (const float*)d_in[17];
  const float* ad3 = (const float*)d_in[18];
  const float* b3 = (const float*)d_in[19];
  const float* mW0 = (const float*)d_in[20];
  const float* mb0 = (const float*)d_in[21];
  const float* mW1 = (const float*)d_in[22];
  const float* mb1 = (const float*)d_in[23];
  const float* mW2 = (const float*)d_in[24];
  const float* mb2 = (const float*)d_in[25];
  float* out = (float*)d_out;

  char* ws = (char*)d_ws;
  size_t cur = 0;
  auto alloc = [&](size_t bytes) -> char* {
    char* p = ws + cur;
    cur += (bytes + 255) & ~(size_t)255;
    return p;
  };
  unsigned short* featA = (unsigned short*)alloc((size_t)N_NODES * 256 * 2);
  unsigned short* hB = (unsigned short*)alloc((size_t)N_NODES * 256 * 2);
  unsigned short* xb = (unsigned short*)alloc((size_t)N_NODES * 64 * 2);
  unsigned short* wt0 = (unsigned short*)alloc((size_t)272 * 64 * 2);
  unsigned short* wt1 = (unsigned short*)alloc((size_t)272 * 256 * 2);
  unsigned short* wt2 = (unsigned short*)alloc((size_t)272 * 256 * 2);
  unsigned short* wt3 = (unsigned short*)alloc((size_t)144 * 256 * 2);
  float* es = (float*)alloc((size_t)N_NODES * 4 * sizeof(float));
  float* ed = (float*)alloc((size_t)N_NODES * 4 * sizeof(float));
  // deg, counter, gcnt contiguous -> single memset
  int* deg = (int*)alloc((size_t)N_NODES * sizeof(int));
  int* counter = (int*)alloc(256);
  int* gcnt = (int*)alloc((size_t)N_GRAPHS_C * sizeof(int));
  size_t zeroBytes = (char*)(gcnt + N_GRAPHS_C) - (char*)deg;
  int* offs = (int*)alloc((size_t)N_NODES * sizeof(int));
  int* cursor = (int*)alloc((size_t)N_NODES * sizeof(int));
  int* csr = (int*)alloc((size_t)E_TOT * sizeof(int));
  int* gptr = (int*)alloc((size_t)N_GRAPHS_C * sizeof(int));
  (void)alloc(128 * 1024);  // slack: GEMM OOB-row over-reads stay in-bounds
  (void)ws_size; (void)in_sizes; (void)n_in; (void)out_size;

  // ---- memset first, then fused conversions + degree/graph counts ----
  hipMemsetAsync(deg, 0, zeroBytes, stream);
  const int cvtTotal = N_NODES * 64 / 4 + 64 * 256 + 2 * 256 * 256 + 256 * 128 +
                       64 * 8 + 2 * 256 * 8 + 256 * 2 + N_EDGES + N_NODES;
  k_cvt_all<<<ceil_div(cvtTotal, 256), 256, 0, stream>>>(
      x, xb, W0, as0, ad0, wt0, W1, as1, ad1, wt1, W2, as2, ad2, wt2, W3, as3, ad3, wt3,
      ei, deg, batch, gcnt);

  // ---- CSR build + graph segments ----
  k_scan<<<ceil_div(N_NODES, 256), 256, 0, stream>>>(deg, offs, cursor, counter);
  k_scatter<<<ceil_div(E_TOT, 256), 256, 0, stream>>>(ei, cursor, csr);
  k_gscan<<<1, 256, 0, stream>>>(gcnt, gptr);

  int gm = ceil_div(N_NODES, 128);
  dim3 g256(gm, 2), g128(gm, 1);
  int aggBlocks = ceil_div(N_NODES, 4);

  // ---- layer 0: 64 -> 4x64 ----
  k_gemm_bf16<1><<<g256, 256, 0, stream>>>(xb, wt0, hB, N_NODES, 64, 256, es, ed);
  k_aggregate<4, 64><<<aggBlocks, 256, 0, stream>>>(hB, es, ed, offs, deg, csr, b0, featA, 1);

  // ---- layer 1 ----
  k_gemm_bf16<1><<<g256, 256, 0, stream>>>(featA, wt1, hB, N_NODES, 256, 256, es, ed);
  k_aggregate<4, 64><<<aggBlocks, 256, 0, stream>>>(hB, es, ed, offs, deg, csr, b1, featA, 1);

  // ---- layer 2 ----
  k_gemm_bf16<1><<<g256, 256, 0, stream>>>(featA, wt2, hB, N_NODES, 256, 256, es, ed);
  k_aggregate<4, 64><<<aggBlocks, 256, 0, stream>>>(hB, es, ed, offs, deg, csr, b2, featA, 1);

  // ---- layer 3: 256 -> 128, 1 head, no ELU ----
  k_gemm_bf16<2><<<g128, 256, 0, stream>>>(featA, wt3, hB, N_NODES, 256, 128, es, ed);
  k_aggregate<1, 128><<<aggBlocks, 256, 0, stream>>>(hB, es, ed, offs, deg, csr, b3, featA, 0);

  // ---- fused pool + readout ----
  k_pool_readout<<<N_GRAPHS_C, 128, 0, stream>>>(featA, gptr, gcnt, mW0, mb0, mW1, mb1, mW2, mb2, out);
}

// Round 16
// 575.095 us; speedup vs baseline: 1.0358x; 1.0358x over previous
//
#include <hip/hip_runtime.h>
#include <math.h>

#define N_NODES 100000
#define N_EDGES 400000
#define N_GRAPHS_C 4096
#define E_TOT (N_EDGES + N_NODES)

static inline int ceil_div(int a, int b) { return (a + b - 1) / b; }

typedef __attribute__((ext_vector_type(8))) short short8v;
typedef __attribute__((ext_vector_type(4))) float float4v;

#define GLL16(g, l)                                                                          \
  __builtin_amdgcn_global_load_lds((const __attribute__((address_space(1))) unsigned int*)(g), \
                                   (__attribute__((address_space(3))) unsigned int*)(l), 16, 0, 0)

__device__ __forceinline__ float b2f(unsigned short u) {
  union { unsigned int i; float f; } v;
  v.i = ((unsigned int)u) << 16;
  return v.f;
}
__device__ __forceinline__ unsigned short f2b(float f) {
  union { float f; unsigned int i; } v;
  v.f = f;
  unsigned int x = v.i;
  unsigned int r = x + 0x7fffu + ((x >> 16) & 1u);  // RNE
  return (unsigned short)(r >> 16);
}

// ---------------- all dtype conversions in one launch ----------------

__device__ __forceinline__ void cvt_one(const float* __restrict__ W, unsigned short* __restrict__ Wt,
                                        int K, int Ncol, int idx) {
  int n = idx / K, k = idx % K;
  Wt[(size_t)n * K + k] = f2b(W[(size_t)k * Ncol + n]);
}

__device__ __forceinline__ void wa_one(const float* __restrict__ W, const float* __restrict__ a_s,
                                       const float* __restrict__ a_d, unsigned short* __restrict__ wt,
                                       int K, int Ncol, int H, int C, int idx) {
  int k = idx % K;
  int j = idx / K;  // 0..2H-1
  const float* a = (j < H) ? a_s : a_d;
  int h = (j < H) ? j : j - H;
  float s = 0.f;
  for (int c = 0; c < C; c++) s += W[(size_t)k * Ncol + h * C + c] * a[h * C + c];
  wt[(size_t)(Ncol + j) * K + k] = f2b(s);
}

__global__ __launch_bounds__(256) void k_cvt_all(
    const float* __restrict__ x, unsigned short* __restrict__ xb,
    const float* __restrict__ W0, const float* __restrict__ as0, const float* __restrict__ ad0, unsigned short* __restrict__ wt0,
    const float* __restrict__ W1, const float* __restrict__ as1, const float* __restrict__ ad1, unsigned short* __restrict__ wt1,
    const float* __restrict__ W2, const float* __restrict__ as2, const float* __restrict__ ad2, unsigned short* __restrict__ wt2,
    const float* __restrict__ W3, const float* __restrict__ as3, const float* __restrict__ ad3, unsigned short* __restrict__ wt3) {
  int i = blockIdx.x * 256 + threadIdx.x;
  const int nx = N_NODES * 64 / 4;
  const int w0e = nx + 64 * 256;
  const int w1e = w0e + 256 * 256;
  const int w2e = w1e + 256 * 256;
  const int w3e = w2e + 256 * 128;
  const int a0e = w3e + 64 * 8;
  const int a1e = a0e + 256 * 8;
  const int a2e = a1e + 256 * 8;
  const int a3e = a2e + 256 * 2;
  if (i < nx) {
    float4 v = *(const float4*)(x + (size_t)i * 4);
    ushort4 o;
    o.x = f2b(v.x); o.y = f2b(v.y); o.z = f2b(v.z); o.w = f2b(v.w);
    *(ushort4*)(xb + (size_t)i * 4) = o;
  } else if (i < w0e) cvt_one(W0, wt0, 64, 256, i - nx);
  else if (i < w1e) cvt_one(W1, wt1, 256, 256, i - w0e);
  else if (i < w2e) cvt_one(W2, wt2, 256, 256, i - w1e);
  else if (i < w3e) cvt_one(W3, wt3, 256, 128, i - w2e);
  else if (i < a0e) wa_one(W0, as0, ad0, wt0, 64, 256, 4, 64, i - w3e);
  else if (i < a1e) wa_one(W1, as1, ad1, wt1, 256, 256, 4, 64, i - a0e);
  else if (i < a2e) wa_one(W2, as2, ad2, wt2, 256, 256, 4, 64, i - a1e);
  else if (i < a3e) wa_one(W3, as3, ad3, wt3, 256, 128, 1, 128, i - a2e);
}

// ---------------- CSR build + graph counts ----------------

__global__ __launch_bounds__(256) void k_count_deg_g(const int* __restrict__ ei, int* __restrict__ deg,
                                                     const int* __restrict__ batch, int* __restrict__ gcnt) {
  int i = blockIdx.x * 256 + threadIdx.x;
  if (i < N_EDGES) atomicAdd(&deg[ei[N_EDGES + i]], 1);
  if (i < N_NODES) atomicAdd(&gcnt[batch[i]], 1);
}

__global__ __launch_bounds__(256) void k_scan(int* __restrict__ deg, int* __restrict__ offs,
                                              int* __restrict__ cursor, int* __restrict__ counter) {
  __shared__ int sm[256];
  __shared__ int sbase;
  int tid = threadIdx.x;
  int n = blockIdx.x * 256 + tid;
  int d = (n < N_NODES) ? (deg[n] + 1) : 0;  // +1 self loop
  sm[tid] = d;
  __syncthreads();
  for (int off = 1; off < 256; off <<= 1) {
    int v = (tid >= off) ? sm[tid - off] : 0;
    __syncthreads();
    sm[tid] += v;
    __syncthreads();
  }
  if (tid == 255) sbase = atomicAdd(counter, sm[255]);
  __syncthreads();
  int excl = sm[tid] - d;
  if (n < N_NODES) {
    int o = sbase + excl;
    offs[n] = o;
    cursor[n] = o;
    deg[n] = d;
  }
}

__global__ __launch_bounds__(256) void k_scatter(const int* __restrict__ ei, int* __restrict__ cursor,
                                                 int* __restrict__ csr) {
  int i = blockIdx.x * 256 + threadIdx.x;
  if (i < N_EDGES) {
    int d = ei[N_EDGES + i];
    int pos = atomicAdd(&cursor[d], 1);
    csr[pos] = ei[i];
  } else if (i < E_TOT) {
    int n = i - N_EDGES;
    int pos = atomicAdd(&cursor[n], 1);
    csr[pos] = n;  // self loop
  }
}

__global__ __launch_bounds__(256) void k_gscan(const int* __restrict__ gcnt, int* __restrict__ gptr) {
  __shared__ int sm[256];
  __shared__ int srun;
  int tid = threadIdx.x;
  if (tid == 0) srun = 0;
  __syncthreads();
  for (int c = 0; c < N_GRAPHS_C / 256; c++) {
    int idx = c * 256 + tid;
    int v = gcnt[idx];
    sm[tid] = v;
    __syncthreads();
    for (int off = 1; off < 256; off <<= 1) {
      int t = (tid >= off) ? sm[tid - off] : 0;
      __syncthreads();
      sm[tid] += t;
      __syncthreads();
    }
    gptr[idx] = srun + sm[tid] - v;
    __syncthreads();
    if (tid == 0) srun += sm[255];
    __syncthreads();
  }
}

// ---------------- bf16 MFMA GEMM with async global->LDS staging ----------------

template <int ATT>
__global__ __launch_bounds__(256) void k_gemm_bf16(const unsigned short* __restrict__ A,
                                                   const unsigned short* __restrict__ Wt,
                                                   unsigned short* __restrict__ out, int M, int K, int Ncol,
                                                   float* __restrict__ es, float* __restrict__ ed) {
  __shared__ unsigned short As[128 * 32];
  __shared__ unsigned short Bs[144 * 32];
  int tid = threadIdx.x;
  int wave = tid >> 6, lane = tid & 63;
  int quad = lane >> 4, l16 = lane & 15;
  int wrow = (wave & 1) * 64, wcol = (wave >> 1) * 64;
  int row0 = blockIdx.x * 128, col0 = blockIdx.y * 128;

  constexpr int EX = (ATT == 1) ? 8 : 2;
  bool blockExtra = (ATT == 1) ? (blockIdx.y == 1) : true;

  float4v acc[4][4];
#pragma unroll
  for (int i = 0; i < 4; i++)
#pragma unroll
    for (int j = 0; j < 4; j++) acc[i][j] = (float4v)(0.f);
  float4v acc_e[4];
#pragma unroll
  for (int i = 0; i < 4; i++) acc_e[i] = (float4v)(0.f);

  int lrow = lane >> 2;
  int lcb = (lane & 3) * 8;
  int ca = wave, cb = wave + 4;

  for (int k0 = 0; k0 < K; k0 += 32) {
    GLL16(A + (size_t)(row0 + ca * 16 + lrow) * K + k0 + lcb, &As[ca * 512]);
    GLL16(A + (size_t)(row0 + cb * 16 + lrow) * K + k0 + lcb, &As[cb * 512]);
    GLL16(Wt + (size_t)(col0 + ca * 16 + lrow) * K + k0 + lcb, &Bs[ca * 512]);
    GLL16(Wt + (size_t)(col0 + cb * 16 + lrow) * K + k0 + lcb, &Bs[cb * 512]);
    if (blockExtra && wave == 0)
      GLL16(Wt + (size_t)(Ncol + lrow) * K + k0 + lcb, &Bs[8 * 512]);
    __syncthreads();

    short8v af[4], bf[4];
#pragma unroll
    for (int i = 0; i < 4; i++)
      af[i] = *(const short8v*)(&As[(wrow + i * 16 + l16) * 32 + quad * 8]);
#pragma unroll
    for (int j = 0; j < 4; j++)
      bf[j] = *(const short8v*)(&Bs[(wcol + j * 16 + l16) * 32 + quad * 8]);
#pragma unroll
    for (int i = 0; i < 4; i++)
#pragma unroll
      for (int j = 0; j < 4; j++)
        acc[i][j] = __builtin_amdgcn_mfma_f32_16x16x32_bf16(af[i], bf[j], acc[i][j], 0, 0, 0);
    if (blockExtra && wcol == 0) {
      short8v bfe = *(const short8v*)(&Bs[(128 + l16) * 32 + quad * 8]);
#pragma unroll
      for (int i = 0; i < 4; i++)
        acc_e[i] = __builtin_amdgcn_mfma_f32_16x16x32_bf16(af[i], bfe, acc_e[i], 0, 0, 0);
    }
    __syncthreads();
  }

#pragma unroll
  for (int i = 0; i < 4; i++) {
#pragma unroll
    for (int r = 0; r < 4; r++) {
      int m = row0 + wrow + i * 16 + quad * 4 + r;
      if (m < M) {
#pragma unroll
        for (int j = 0; j < 4; j++) {
          int col = col0 + wcol + j * 16 + l16;
          out[(size_t)m * Ncol + col] = f2b(acc[i][j][r]);
        }
      }
    }
  }

  if (blockExtra && wcol == 0 && l16 < EX) {
    constexpr int H = (ATT == 1) ? 4 : 1;
    float* dst = (l16 < H) ? es : ed;
    int h = (l16 < H) ? l16 : l16 - H;
#pragma unroll
    for (int i = 0; i < 4; i++) {
#pragma unroll
      for (int r = 0; r < 4; r++) {
        int m = row0 + wrow + i * 16 + quad * 4 + r;
        if (m < M) dst[m * H + h] = acc_e[i][r];
      }
    }
  }
}

// ---------------- fused logits + softmax + aggregation ----------------

__device__ __forceinline__ void acc4(float* acc, float w, uint2 u) {
  acc[0] += w * b2f((unsigned short)(u.x & 0xffff));
  acc[1] += w * b2f((unsigned short)(u.x >> 16));
  acc[2] += w * b2f((unsigned short)(u.y & 0xffff));
  acc[3] += w * b2f((unsigned short)(u.y >> 16));
}
__device__ __forceinline__ void acc2(float* acc, float w, unsigned int u) {
  acc[0] += w * b2f((unsigned short)(u & 0xffff));
  acc[1] += w * b2f((unsigned short)(u >> 16));
}
__device__ __forceinline__ float lrelu_exp(float e) {
  e = e > 0.f ? e : 0.2f * e;
  return __expf(e);
}

template <int H, int C>
__global__ __launch_bounds__(256) void k_aggregate(const unsigned short* __restrict__ hbuf,
                                                   const float* __restrict__ es, const float* __restrict__ ed,
                                                   const int* __restrict__ offs, const int* __restrict__ deg,
                                                   const int* __restrict__ csr, const float* __restrict__ bias,
                                                   unsigned short* __restrict__ out, int applyElu) {
  constexpr int F = H * C;
  constexpr int VPL = F / 64;  // 4 (H=4,C=64) or 2 (H=1,C=128)
  int wave = threadIdx.x >> 6;
  int lane = threadIdx.x & 63;
  int n = blockIdx.x * 4 + wave;
  if (n >= N_NODES) return;
  int head = (H == 1) ? 0 : (lane >> 4);
  int start = offs[n];
  int cnt = deg[n];
  const int* csrp = csr + start;
  float edn = ed[n * H + head];

  float acc[VPL];
#pragma unroll
  for (int j = 0; j < VPL; j++) acc[j] = 0.f;
  float dsum = 0.f;

  int i = 0;
  for (; i + 4 <= cnt; i += 4) {
    int s0 = csrp[i], s1 = csrp[i + 1], s2 = csrp[i + 2], s3 = csrp[i + 3];
    float w0 = lrelu_exp(es[s0 * H + head] + edn);
    float w1 = lrelu_exp(es[s1 * H + head] + edn);
    float w2 = lrelu_exp(es[s2 * H + head] + edn);
    float w3 = lrelu_exp(es[s3 * H + head] + edn);
    dsum += (w0 + w1) + (w2 + w3);
    if (VPL == 4) {
      uint2 u0 = *(const uint2*)(hbuf + (size_t)s0 * F + lane * 4);
      uint2 u1 = *(const uint2*)(hbuf + (size_t)s1 * F + lane * 4);
      uint2 u2 = *(const uint2*)(hbuf + (size_t)s2 * F + lane * 4);
      uint2 u3 = *(const uint2*)(hbuf + (size_t)s3 * F + lane * 4);
      acc4(acc, w0, u0); acc4(acc, w1, u1); acc4(acc, w2, u2); acc4(acc, w3, u3);
    } else {
      unsigned int u0 = *(const unsigned int*)(hbuf + (size_t)s0 * F + lane * 2);
      unsigned int u1 = *(const unsigned int*)(hbuf + (size_t)s1 * F + lane * 2);
      unsigned int u2 = *(const unsigned int*)(hbuf + (size_t)s2 * F + lane * 2);
      unsigned int u3 = *(const unsigned int*)(hbuf + (size_t)s3 * F + lane * 2);
      acc2(acc, w0, u0); acc2(acc, w1, u1); acc2(acc, w2, u2); acc2(acc, w3, u3);
    }
  }
  for (; i < cnt; i++) {
    int s = csrp[i];
    float w = lrelu_exp(es[s * H + head] + edn);
    dsum += w;
    if (VPL == 4) {
      uint2 u = *(const uint2*)(hbuf + (size_t)s * F + lane * 4);
      acc4(acc, w, u);
    } else {
      unsigned int u = *(const unsigned int*)(hbuf + (size_t)s * F + lane * 2);
      acc2(acc, w, u);
    }
  }

  float iv = 1.0f / fmaxf(dsum, 1e-16f);
  unsigned short ob[VPL];
#pragma unroll
  for (int j = 0; j < VPL; j++) {
    float v = acc[j] * iv + bias[lane * VPL + j];
    if (applyElu) v = v > 0.f ? v : expm1f(v);
    ob[j] = f2b(v);
  }
  if (VPL == 4) {
    ushort4 o = make_ushort4(ob[0], ob[1], ob[2], ob[3]);
    *(ushort4*)(out + (size_t)n * F + lane * 4) = o;
  } else {
    ushort2 o = make_ushort2(ob[0], ob[1]);
    *(ushort2*)(out + (size_t)n * F + lane * 2) = o;
  }
}

// ---------------- fused per-graph mean pool + MLP readout ----------------

__global__ __launch_bounds__(128) void k_pool_readout(const unsigned short* __restrict__ feat,
                                                      const int* __restrict__ gptr, const int* __restrict__ gcnt,
                                                      const float* __restrict__ mW0, const float* __restrict__ mb0,
                                                      const float* __restrict__ mW1, const float* __restrict__ mb1,
                                                      const float* __restrict__ mW2, const float* __restrict__ mb2,
                                                      float* __restrict__ out) {
  __shared__ float part[2][128];
  __shared__ float p[128];
  __shared__ float y1[64];
  __shared__ float y2[32];
  int g = blockIdx.x;
  int t = threadIdx.x;
  int w = t >> 6, lane = t & 63;
  int start = gptr[g];
  int c = gcnt[g];
  float a0 = 0.f, a1 = 0.f;
  for (int i = w; i < c; i += 2) {
    unsigned int u = *(const unsigned int*)(feat + (size_t)(start + i) * 128 + lane * 2);
    a0 += b2f((unsigned short)(u & 0xffff));
    a1 += b2f((unsigned short)(u >> 16));
  }
  part[w][lane * 2 + 0] = a0;
  part[w][lane * 2 + 1] = a1;
  __syncthreads();
  float invc = 1.0f / fmaxf((float)c, 1.0f);
  p[t] = (part[0][t] + part[1][t]) * invc;
  __syncthreads();
  if (t < 64) {
    float v = mb0[t];
#pragma unroll 4
    for (int k = 0; k < 128; k++) v += p[k] * mW0[k * 64 + t];
    y1[t] = v > 0.f ? v : 0.f;
  }
  __syncthreads();
  if (t < 32) {
    float v = mb1[t];
#pragma unroll 4
    for (int k = 0; k < 64; k++) v += y1[k] * mW1[k * 32 + t];
    y2[t] = v > 0.f ? v : 0.f;
  }
  __syncthreads();
  if (t < 4) {
    float v = mb2[t];
#pragma unroll 4
    for (int k = 0; k < 32; k++) v += y2[k] * mW2[k * 4 + t];
    out[(size_t)g * 4 + t] = v;
  }
}

// ---------------- host side ----------------

extern "C" void kernel_launch(void* const* d_in, const int* in_sizes, int n_in,
                              void* d_out, int out_size, void* d_ws, size_t ws_size,
                              hipStream_t stream) {
  const float* x = (const float*)d_in[0];
  const int* ei = (const int*)d_in[1];
  const int* batch = (const int*)d_in[2];
  const float* W0 = (const float*)d_in[4];
  const float* as0 = (const float*)d_in[5];
  const float* ad0 = (const float*)d_in[6];
  const float* b0 = (const float*)d_in[7];
  const float* W1 = (const float*)d_in[8];
  const float* as1 = (const float*)d_in[9];
  const float* ad1 = (const float*)d_in[10];
  const float* b1 = (const float*)d_in[11];
  const float* W2 = (const float*)d_in[12];
  const float* as2 = (const float*)d_in[13];
  const float* ad2 = (const float*)d_in[14];
  const float* b2 = (const float*)d_in[15];
  const float* W3 = (const float*)d_in[16];
  const float* as3 = (const float*)d_in[17];
  const float* ad3 = (const float*)d_in[18];
  const float* b3 = (const float*)d_in[19];
  const float* mW0 = (const float*)d_in[20];
  const float* mb0 = (const float*)d_in[21];
  const float* mW1 = (const float*)d_in[22];
  const float* mb1 = (const float*)d_in[23];
  const float* mW2 = (const float*)d_in[24];
  const float* mb2 = (const float*)d_in[25];
  float* out = (float*)d_out;

  char* ws = (char*)d_ws;
  size_t cur = 0;
  auto alloc = [&](size_t bytes) -> char* {
    char* p = ws + cur;
    cur += (bytes + 255) & ~(size_t)255;
    return p;
  };
  unsigned short* featA = (unsigned short*)alloc((size_t)N_NODES * 256 * 2);
  unsigned short* hB = (unsigned short*)alloc((size_t)N_NODES * 256 * 2);
  unsigned short* xb = (unsigned short*)alloc((size_t)N_NODES * 64 * 2);
  unsigned short* wt0 = (unsigned short*)alloc((size_t)272 * 64 * 2);
  unsigned short* wt1 = (unsigned short*)alloc((size_t)272 * 256 * 2);
  unsigned short* wt2 = (unsigned short*)alloc((size_t)272 * 256 * 2);
  unsigned short* wt3 = (unsigned short*)alloc((size_t)144 * 256 * 2);
  float* es = (float*)alloc((size_t)N_NODES * 4 * sizeof(float));
  float* ed = (float*)alloc((size_t)N_NODES * 4 * sizeof(float));
  // deg, counter, gcnt contiguous -> single memset
  int* deg = (int*)alloc((size_t)N_NODES * sizeof(int));
  int* counter = (int*)alloc(256);
  int* gcnt = (int*)alloc((size_t)N_GRAPHS_C * sizeof(int));
  size_t zeroBytes = (char*)(gcnt + N_GRAPHS_C) - (char*)deg;
  int* offs = (int*)alloc((size_t)N_NODES * sizeof(int));
  int* cursor = (int*)alloc((size_t)N_NODES * sizeof(int));
  int* csr = (int*)alloc((size_t)E_TOT * sizeof(int));
  int* gptr = (int*)alloc((size_t)N_GRAPHS_C * sizeof(int));
  (void)alloc(128 * 1024);  // slack: GEMM OOB-row over-reads stay in-bounds
  (void)ws_size; (void)in_sizes; (void)n_in; (void)out_size;

  // ---- conversions (single launch) ----
  const int cvtTotal = N_NODES * 64 / 4 + 64 * 256 + 2 * 256 * 256 + 256 * 128 +
                       64 * 8 + 2 * 256 * 8 + 256 * 2;
  k_cvt_all<<<ceil_div(cvtTotal, 256), 256, 0, stream>>>(
      x, xb, W0, as0, ad0, wt0, W1, as1, ad1, wt1, W2, as2, ad2, wt2, W3, as3, ad3, wt3);

  // ---- CSR build + graph segments ----
  hipMemsetAsync(deg, 0, zeroBytes, stream);
  k_count_deg_g<<<ceil_div(N_EDGES, 256), 256, 0, stream>>>(ei, deg, batch, gcnt);
  k_scan<<<ceil_div(N_NODES, 256), 256, 0, stream>>>(deg, offs, cursor, counter);
  k_scatter<<<ceil_div(E_TOT, 256), 256, 0, stream>>>(ei, cursor, csr);
  k_gscan<<<1, 256, 0, stream>>>(gcnt, gptr);

  int gm = ceil_div(N_NODES, 128);
  dim3 g256(gm, 2), g128(gm, 1);
  int aggBlocks = ceil_div(N_NODES, 4);

  // ---- layer 0: 64 -> 4x64 ----
  k_gemm_bf16<1><<<g256, 256, 0, stream>>>(xb, wt0, hB, N_NODES, 64, 256, es, ed);
  k_aggregate<4, 64><<<aggBlocks, 256, 0, stream>>>(hB, es, ed, offs, deg, csr, b0, featA, 1);

  // ---- layer 1 ----
  k_gemm_bf16<1><<<g256, 256, 0, stream>>>(featA, wt1, hB, N_NODES, 256, 256, es, ed);
  k_aggregate<4, 64><<<aggBlocks, 256, 0, stream>>>(hB, es, ed, offs, deg, csr, b1, featA, 1);

  // ---- layer 2 ----
  k_gemm_bf16<1><<<g256, 256, 0, stream>>>(featA, wt2, hB, N_NODES, 256, 256, es, ed);
  k_aggregate<4, 64><<<aggBlocks, 256, 0, stream>>>(hB, es, ed, offs, deg, csr, b2, featA, 1);

  // ---- layer 3: 256 -> 128, 1 head, no ELU ----
  k_gemm_bf16<2><<<g128, 256, 0, stream>>>(featA, wt3, hB, N_NODES, 256, 128, es, ed);
  k_aggregate<1, 128><<<aggBlocks, 256, 0, stream>>>(hB, es, ed, offs, deg, csr, b3, featA, 0);

  // ---- fused pool + readout ----
  k_pool_readout<<<N_GRAPHS_C, 128, 0, stream>>>(featA, gptr, gcnt, mW0, mb0, mW1, mb1, mW2, mb2, out);
}